// Round 2
// baseline (225.649 us; speedup 1.0000x reference)
//
#include <hip/hip_runtime.h>
#include <math.h>

#define Bn 256
#define Dm 256
#define Hm 512
#define Em 64
#define NL 1024
#define TOPK 10
#define GS 8          // samples per expert group
#define MAXG 88       // max groups: 64 + (256-64)/8

// ================= root MLP fused (2 samples per block) =================
__global__ __launch_bounds__(256) void root_fused_kernel(
        const float* __restrict__ state,
        const float* __restrict__ rW1, const float* __restrict__ rb1,
        const float* __restrict__ rW2, const float* __restrict__ rb2,
        const float* __restrict__ rW3, const float* __restrict__ rb3,
        int* __restrict__ idx_out, float* __restrict__ rlp_out) {
    __shared__ float sx[2 * Dm];
    __shared__ float sh1[2][Hm];
    __shared__ float sh2[2][Hm];
    const int tid = threadIdx.x;
    const int b0 = blockIdx.x * 2;

    for (int k = tid; k < 2 * Dm; k += 256) sx[k] = state[b0 * Dm + k];
    __syncthreads();

    // L1: 256 -> 512, thread t owns cols 2t,2t+1 for both samples
    {
        const int j = 2 * tid;
        float a00 = rb1[j], a01 = rb1[j + 1];
        float a10 = a00, a11 = a01;
        for (int i = 0; i < Dm; ++i) {
            float2 w = *(const float2*)(rW1 + (size_t)i * Hm + j);
            float x0 = sx[i], x1 = sx[Dm + i];
            a00 = fmaf(x0, w.x, a00); a01 = fmaf(x0, w.y, a01);
            a10 = fmaf(x1, w.x, a10); a11 = fmaf(x1, w.y, a11);
        }
        sh1[0][j] = fmaxf(a00, 0.f); sh1[0][j + 1] = fmaxf(a01, 0.f);
        sh1[1][j] = fmaxf(a10, 0.f); sh1[1][j + 1] = fmaxf(a11, 0.f);
    }
    __syncthreads();

    // L2: 512 -> 512
    {
        const int j = 2 * tid;
        float a00 = rb2[j], a01 = rb2[j + 1];
        float a10 = a00, a11 = a01;
        for (int i = 0; i < Hm; ++i) {
            float2 w = *(const float2*)(rW2 + (size_t)i * Hm + j);
            float x0 = sh1[0][i], x1 = sh1[1][i];
            a00 = fmaf(x0, w.x, a00); a01 = fmaf(x0, w.y, a01);
            a10 = fmaf(x1, w.x, a10); a11 = fmaf(x1, w.y, a11);
        }
        sh2[0][j] = fmaxf(a00, 0.f); sh2[0][j + 1] = fmaxf(a01, 0.f);
        sh2[1][j] = fmaxf(a10, 0.f); sh2[1][j + 1] = fmaxf(a11, 0.f);
    }
    __syncthreads();

    // L3: 512 -> 64, argmax + log-softmax-at-argmax. t<128: wave s holds all 64 cols.
    if (tid < 128) {
        const int j = tid & 63;
        const int s = tid >> 6;
        float acc = rb3[j];
        for (int i = 0; i < Hm; ++i) acc = fmaf(sh2[s][i], rW3[(size_t)i * Em + j], acc);
        float v = acc; int bi = j;
        #pragma unroll
        for (int off = 32; off; off >>= 1) {
            float ov = __shfl_xor(v, off);
            int   oi = __shfl_xor(bi, off);
            if (ov > v || (ov == v && oi < bi)) { v = ov; bi = oi; }
        }
        float ssum = expf(acc - v);
        #pragma unroll
        for (int off = 32; off; off >>= 1) ssum += __shfl_xor(ssum, off);
        if (j == 0) {
            idx_out[b0 + s] = bi;
            rlp_out[b0 + s] = -logf(ssum);
        }
    }
}

// ================= routing: perm + group table =================
__global__ void routing_kernel(const int* __restrict__ idx, int* __restrict__ perm,
                               int4* __restrict__ groups) {
    __shared__ int cnt[Em];
    __shared__ int offs[Em];
    const int tid = threadIdx.x;  // 256 threads
    if (tid < Em) cnt[tid] = 0;
    __syncthreads();
    const int e = idx[tid];
    const int r = atomicAdd(&cnt[e], 1);
    __syncthreads();
    if (tid == 0) {
        int run = 0, g = 0;
        for (int ee = 0; ee < Em; ++ee) {
            offs[ee] = run;
            const int n = cnt[ee];
            for (int k = 0; k < n; k += GS)
                groups[g++] = make_int4(ee, run + k, min(GS, n - k), 0);
            run += n;
        }
        for (; g < MAXG; ++g) groups[g] = make_int4(0, 0, 0, 0);
    }
    __syncthreads();
    perm[offs[e] + r] = tid;
}

// ================= grouped expert dense layer =================
// block = 64 threads (1 wave); each thread owns 4 consecutive out-cols (float4),
// 8 samples => 32 accumulators, 32 FMA per 16B weight load.
template<int IN, int OUT, bool RELU>
__global__ __launch_bounds__(64) void grouped_dense_kernel(
        const float* __restrict__ X, const int* __restrict__ perm,
        const float* __restrict__ W, const float* __restrict__ Bv,
        const int4* __restrict__ groups, float* __restrict__ Y) {
    const int4 g = groups[blockIdx.x];
    const int cnt = g.z;
    if (cnt == 0) return;
    const int e = g.x, p0 = g.y;
    __shared__ float sxT[IN * GS];  // transposed: [i][c]
    const int tid = threadIdx.x;

    for (int c = 0; c < GS; ++c) {
        if (c < cnt) {
            const int row = perm ? perm[p0 + c] : (p0 + c);
            const float* xr = X + (size_t)row * IN;
            for (int i4 = tid; i4 < IN / 4; i4 += 64) {
                float4 x = *(const float4*)(xr + i4 * 4);
                sxT[(i4 * 4 + 0) * GS + c] = x.x;
                sxT[(i4 * 4 + 1) * GS + c] = x.y;
                sxT[(i4 * 4 + 2) * GS + c] = x.z;
                sxT[(i4 * 4 + 3) * GS + c] = x.w;
            }
        } else {
            for (int i = tid; i < IN; i += 64) sxT[i * GS + c] = 0.f;
        }
    }
    __syncthreads();

    const int col = (blockIdx.y * 64 + tid) * 4;
    const float* We = W + (size_t)e * IN * OUT + col;
    const float4 bv = *(const float4*)(Bv + (size_t)e * OUT + col);
    float acc[GS][4];
    #pragma unroll
    for (int c = 0; c < GS; ++c) {
        acc[c][0] = bv.x; acc[c][1] = bv.y; acc[c][2] = bv.z; acc[c][3] = bv.w;
    }

    #pragma unroll 4
    for (int i = 0; i < IN; ++i) {
        const float4 w = *(const float4*)(We + (size_t)i * OUT);
        const float4 xa = *(const float4*)&sxT[i * GS];
        const float4 xb = *(const float4*)&sxT[i * GS + 4];
        const float xs[GS] = {xa.x, xa.y, xa.z, xa.w, xb.x, xb.y, xb.z, xb.w};
        #pragma unroll
        for (int c = 0; c < GS; ++c) {
            acc[c][0] = fmaf(xs[c], w.x, acc[c][0]);
            acc[c][1] = fmaf(xs[c], w.y, acc[c][1]);
            acc[c][2] = fmaf(xs[c], w.z, acc[c][2]);
            acc[c][3] = fmaf(xs[c], w.w, acc[c][3]);
        }
    }

    for (int c = 0; c < cnt; ++c) {
        float4 o;
        if (RELU) {
            o.x = fmaxf(acc[c][0], 0.f); o.y = fmaxf(acc[c][1], 0.f);
            o.z = fmaxf(acc[c][2], 0.f); o.w = fmaxf(acc[c][3], 0.f);
        } else {
            o.x = acc[c][0]; o.y = acc[c][1]; o.z = acc[c][2]; o.w = acc[c][3];
        }
        *(float4*)(Y + (size_t)(p0 + c) * OUT + col) = o;
    }
}

// ================= log-softmax + top-11 + filter + outputs =================
__global__ __launch_bounds__(256) void topk_kernel(
        const float* __restrict__ logits, const int* __restrict__ perm,
        const int* __restrict__ idx, const float* __restrict__ rlp,
        float* __restrict__ out) {
    __shared__ float sl[NL];
    __shared__ float redA[4];
    __shared__ float redB[4];
    __shared__ float bcast[2];
    const int p = blockIdx.x;
    const int tid = threadIdx.x;
    const int b = perm[p];
    const int e = idx[b];
    const float* row = logits + (size_t)p * NL;

    const float4 v4 = *(const float4*)(row + tid * 4);
    *(float4*)&sl[tid * 4] = v4;

    float m = fmaxf(fmaxf(v4.x, v4.y), fmaxf(v4.z, v4.w));
    #pragma unroll
    for (int off = 32; off; off >>= 1) m = fmaxf(m, __shfl_xor(m, off));
    const int wid = tid >> 6;
    if ((tid & 63) == 0) redA[wid] = m;
    __syncthreads();
    if (tid == 0) {
        float mm = redA[0];
        #pragma unroll
        for (int w = 1; w < 4; ++w) mm = fmaxf(mm, redA[w]);
        bcast[0] = mm;
    }
    __syncthreads();
    m = bcast[0];

    float s = expf(v4.x - m) + expf(v4.y - m) + expf(v4.z - m) + expf(v4.w - m);
    #pragma unroll
    for (int off = 32; off; off >>= 1) s += __shfl_xor(s, off);
    if ((tid & 63) == 0) redB[wid] = s;
    __syncthreads();
    if (tid == 0) {
        float ss = 0.f;
        #pragma unroll
        for (int w = 0; w < 4; ++w) ss += redB[w];
        bcast[1] = m + logf(ss);
    }
    __syncthreads();
    const float logZ = bcast[1];

    if (tid < 64) {
        float vals[16];
        #pragma unroll
        for (int q = 0; q < 16; ++q) vals[q] = sl[tid * 16 + q];
        float selv[11];
        int   seli[11];
        for (int t = 0; t < 11; ++t) {
            float v = -INFINITY; int bq = 0;
            #pragma unroll
            for (int q = 0; q < 16; ++q) {
                if (vals[q] > v) { v = vals[q]; bq = q; }  // first occurrence on ties
            }
            int gi = tid * 16 + bq;
            #pragma unroll
            for (int off = 32; off; off >>= 1) {
                float ov = __shfl_xor(v, off);
                int   oi = __shfl_xor(gi, off);
                if (ov > v || (ov == v && oi < gi)) { v = ov; gi = oi; }
            }
            selv[t] = v;
            seli[t] = gi;
            if ((gi >> 4) == tid) vals[gi & 15] = -INFINITY;
        }
        if (tid == 0) {
            const float rl = rlp[b];
            int cnt = 0;
            for (int t = 0; t < 11 && cnt < TOPK; ++t) {
                if (seli[t] == 0 && e == 0) continue;  // drop the (0,0) trajectory
                out[(b * TOPK + cnt) * 2 + 0] = (float)e;
                out[(b * TOPK + cnt) * 2 + 1] = (float)seli[t];
                out[Bn * TOPK * 2 + b * TOPK + cnt] = selv[t] - logZ + rl;
                ++cnt;
            }
        }
    }
}

extern "C" void kernel_launch(void* const* d_in, const int* in_sizes, int n_in,
                              void* d_out, int out_size, void* d_ws, size_t ws_size,
                              hipStream_t stream) {
    const float* state = (const float*)d_in[0];
    const float* rW1   = (const float*)d_in[1];
    const float* rb1   = (const float*)d_in[2];
    const float* rW2   = (const float*)d_in[3];
    const float* rb2   = (const float*)d_in[4];
    const float* rW3   = (const float*)d_in[5];
    const float* rb3   = (const float*)d_in[6];
    const float* eW1   = (const float*)d_in[7];
    const float* eb1   = (const float*)d_in[8];
    const float* eW2   = (const float*)d_in[9];
    const float* eb2   = (const float*)d_in[10];
    const float* eW3   = (const float*)d_in[11];
    const float* eb3   = (const float*)d_in[12];
    float* out = (float*)d_out;

    float* eh1    = (float*)d_ws;            // [256][512] permuted
    float* eh2    = eh1 + Bn * Hm;           // [256][512] permuted
    float* logits = eh2 + Bn * Hm;           // [256][1024] permuted
    float* rlp    = logits + Bn * NL;        // [256]
    int*   idxp   = (int*)(rlp + Bn);        // [256]
    int*   perm   = idxp + Bn;               // [256]
    int4*  groups = (int4*)(perm + Bn);      // [88]

    root_fused_kernel<<<Bn / 2, 256, 0, stream>>>(state, rW1, rb1, rW2, rb2, rW3, rb3,
                                                  idxp, rlp);
    routing_kernel<<<1, 256, 0, stream>>>(idxp, perm, groups);
    grouped_dense_kernel<Dm, Hm, true><<<dim3(MAXG, Hm / 256), 64, 0, stream>>>(
        state, perm, eW1, eb1, groups, eh1);
    grouped_dense_kernel<Hm, Hm, true><<<dim3(MAXG, Hm / 256), 64, 0, stream>>>(
        eh1, nullptr, eW2, eb2, groups, eh2);
    grouped_dense_kernel<Hm, NL, false><<<dim3(MAXG, NL / 256), 64, 0, stream>>>(
        eh2, nullptr, eW3, eb3, groups, logits);
    topk_kernel<<<Bn, 256, 0, stream>>>(logits, perm, idxp, rlp, out);
}

// Round 3
// 97.240 us; speedup vs baseline: 2.3205x; 2.3205x over previous
//
#include <hip/hip_runtime.h>
#include <math.h>

#define Bn 256
#define Dm 256
#define Hm 512
#define Em 64
#define NL 1024
#define TOPK 10
#define GS 8          // samples per expert group (= MT for grouped layers)
#define MAXG 88       // max groups: 64 + (256-64)/8

// ============ generic K-split dense layer ============
// MT samples staged transposed in LDS; NW waves each own a K-chunk; lane owns 4
// consecutive out-cols (float4 weight loads, 4*MT FMA per 16B load); partials
// reduced deterministically in LDS (waves >=4 fold into slots 0-3 first).
template<int IN, int OUT, int MT, int CCH, int NW, bool RELU, bool GROUPED>
__global__ __launch_bounds__(NW * 64) void dense_ks(
        const float* __restrict__ X, const int* __restrict__ perm,
        const float* __restrict__ W, const float* __restrict__ Bv,
        const int4* __restrict__ groups, float* __restrict__ Y) {
    constexpr int NT  = NW * 64;
    constexpr int KCH = IN / NW;
    constexpr int NR  = (NW > 4) ? 4 : NW;   // reduction slots
    static_assert(CCH == 256 && MT == 8, "");

    int e, p0, cnt;
    if (GROUPED) {
        const int4 g = groups[blockIdx.x];
        if (g.z == 0) return;
        e = g.x; p0 = g.y; cnt = g.z;
    } else {
        e = 0; p0 = blockIdx.x * MT; cnt = MT;
    }

    __shared__ float sxT[IN * MT];          // [i][c] transposed activations
    __shared__ float part[NR * MT * CCH];   // partial sums
    const int tid = threadIdx.x;

    // stage activations transposed; c = j&7 keeps LDS writes conflict-light
    for (int j = tid; j < (IN / 4) * MT; j += NT) {
        const int c  = j & (MT - 1);
        const int i4 = j >> 3;
        float4 x = make_float4(0.f, 0.f, 0.f, 0.f);
        if (c < cnt) {
            int row;
            if (GROUPED) row = perm ? perm[p0 + c] : (p0 + c);
            else         row = p0 + c;
            x = *(const float4*)(X + (size_t)row * IN + i4 * 4);
        }
        sxT[(i4 * 4 + 0) * MT + c] = x.x;
        sxT[(i4 * 4 + 1) * MT + c] = x.y;
        sxT[(i4 * 4 + 2) * MT + c] = x.z;
        sxT[(i4 * 4 + 3) * MT + c] = x.w;
    }
    __syncthreads();

    const int wave = tid >> 6, lane = tid & 63;
    const int colb = blockIdx.y * CCH;
    const int col  = colb + lane * 4;
    const int k0   = wave * KCH;
    const float* We = W + (size_t)e * IN * OUT + (size_t)k0 * OUT + col;

    float acc[MT][4];
    #pragma unroll
    for (int c = 0; c < MT; ++c) { acc[c][0]=0.f; acc[c][1]=0.f; acc[c][2]=0.f; acc[c][3]=0.f; }

    #pragma unroll 4
    for (int i = 0; i < KCH; ++i) {
        const float4 w = *(const float4*)(We + (size_t)i * OUT);
        const float* xr = &sxT[(k0 + i) * MT];
        const float4 xa = *(const float4*)xr;
        const float4 xb = *(const float4*)(xr + 4);
        const float xs[MT] = {xa.x, xa.y, xa.z, xa.w, xb.x, xb.y, xb.z, xb.w};
        #pragma unroll
        for (int c = 0; c < MT; ++c) {
            acc[c][0] = fmaf(xs[c], w.x, acc[c][0]);
            acc[c][1] = fmaf(xs[c], w.y, acc[c][1]);
            acc[c][2] = fmaf(xs[c], w.z, acc[c][2]);
            acc[c][3] = fmaf(xs[c], w.w, acc[c][3]);
        }
    }

    // stage 1: waves 0..NR-1 write their partials
    if (wave < NR) {
        #pragma unroll
        for (int c = 0; c < MT; ++c)
            *(float4*)&part[((wave * MT) + c) * CCH + lane * 4] = *(const float4*)acc[c];
    }
    __syncthreads();
    // stage 2: waves NR..NW-1 fold into slot (wave-NR)  (distinct slots -> race-free)
    if (NW > NR) {
        if (wave >= NR) {
            #pragma unroll
            for (int c = 0; c < MT; ++c) {
                float4* p = (float4*)&part[(((wave - NR) * MT) + c) * CCH + lane * 4];
                float4 v = *p;
                v.x += acc[c][0]; v.y += acc[c][1]; v.z += acc[c][2]; v.w += acc[c][3];
                *p = v;
            }
        }
        __syncthreads();
    }

    // final reduce over NR slots + bias (+relu) + store
    for (int j = tid; j < MT * (CCH / 4); j += NT) {
        const int c = j / (CCH / 4);
        const int q = j % (CCH / 4);
        float4 s = *(const float4*)&part[c * CCH + q * 4];
        #pragma unroll
        for (int w = 1; w < NR; ++w) {
            const float4 p = *(const float4*)&part[((w * MT) + c) * CCH + q * 4];
            s.x += p.x; s.y += p.y; s.z += p.z; s.w += p.w;
        }
        if (c < cnt) {
            const float4 b = *(const float4*)(Bv + (size_t)e * OUT + colb + q * 4);
            s.x += b.x; s.y += b.y; s.z += b.z; s.w += b.w;
            if (RELU) {
                s.x = fmaxf(s.x, 0.f); s.y = fmaxf(s.y, 0.f);
                s.z = fmaxf(s.z, 0.f); s.w = fmaxf(s.w, 0.f);
            }
            *(float4*)(Y + (size_t)(p0 + c) * OUT + colb + q * 4) = s;
        }
    }
}

// ============ root layer 3 (512 -> 64) + argmax + log-softmax at argmax ============
// 8 samples per block, 8 waves split K=512; lane = output col.
__global__ __launch_bounds__(512) void root3_ks(
        const float* __restrict__ H2, const float* __restrict__ W,
        const float* __restrict__ bias, int* __restrict__ idx_out,
        float* __restrict__ rlp_out) {
    __shared__ float sxT[Hm * 8];
    __shared__ float part[8 * 8 * Em];
    __shared__ float fin[8][Em];
    const int tid = threadIdx.x;
    const int b0 = blockIdx.x * 8;

    for (int j = tid; j < (Hm / 4) * 8; j += 512) {
        const int c = j & 7, i4 = j >> 3;
        const float4 x = *(const float4*)(H2 + (size_t)(b0 + c) * Hm + i4 * 4);
        sxT[(i4 * 4 + 0) * 8 + c] = x.x;
        sxT[(i4 * 4 + 1) * 8 + c] = x.y;
        sxT[(i4 * 4 + 2) * 8 + c] = x.z;
        sxT[(i4 * 4 + 3) * 8 + c] = x.w;
    }
    __syncthreads();

    const int wave = tid >> 6, lane = tid & 63;
    const int k0 = wave * 64;
    float acc[8] = {0.f,0.f,0.f,0.f,0.f,0.f,0.f,0.f};
    #pragma unroll 4
    for (int i = 0; i < 64; ++i) {
        const float w = W[(size_t)(k0 + i) * Em + lane];
        const float* xr = &sxT[(k0 + i) * 8];
        const float4 xa = *(const float4*)xr;
        const float4 xb = *(const float4*)(xr + 4);
        acc[0] = fmaf(xa.x, w, acc[0]); acc[1] = fmaf(xa.y, w, acc[1]);
        acc[2] = fmaf(xa.z, w, acc[2]); acc[3] = fmaf(xa.w, w, acc[3]);
        acc[4] = fmaf(xb.x, w, acc[4]); acc[5] = fmaf(xb.y, w, acc[5]);
        acc[6] = fmaf(xb.z, w, acc[6]); acc[7] = fmaf(xb.w, w, acc[7]);
    }
    #pragma unroll
    for (int c = 0; c < 8; ++c) part[(wave * 8 + c) * Em + lane] = acc[c];
    __syncthreads();

    {   // 512 threads cover exactly 8 samples x 64 cols
        const int c = wave, colj = lane;
        float s = bias[colj];
        #pragma unroll
        for (int w = 0; w < 8; ++w) s += part[(w * 8 + c) * Em + colj];
        fin[c][colj] = s;
    }
    __syncthreads();

    {   // wave w handles sample w: argmax (tie -> smaller idx) + lse
        const int c = wave;
        const float a0 = fin[c][lane];
        float v = a0; int bi = lane;
        #pragma unroll
        for (int off = 32; off; off >>= 1) {
            const float ov = __shfl_xor(v, off);
            const int   oi = __shfl_xor(bi, off);
            if (ov > v || (ov == v && oi < bi)) { v = ov; bi = oi; }
        }
        float ssum = expf(a0 - v);
        #pragma unroll
        for (int off = 32; off; off >>= 1) ssum += __shfl_xor(ssum, off);
        if (lane == 0) { idx_out[b0 + c] = bi; rlp_out[b0 + c] = -logf(ssum); }
    }
}

// ============ routing: perm + group table ============
__global__ void routing_kernel(const int* __restrict__ idx, int* __restrict__ perm,
                               int4* __restrict__ groups) {
    __shared__ int cnt[Em];
    __shared__ int offs[Em];
    const int tid = threadIdx.x;  // 256 threads
    if (tid < Em) cnt[tid] = 0;
    __syncthreads();
    const int e = idx[tid];
    const int r = atomicAdd(&cnt[e], 1);
    __syncthreads();
    if (tid == 0) {
        int run = 0, g = 0;
        for (int ee = 0; ee < Em; ++ee) {
            offs[ee] = run;
            const int n = cnt[ee];
            for (int k = 0; k < n; k += GS)
                groups[g++] = make_int4(ee, run + k, min(GS, n - k), 0);
            run += n;
        }
        for (; g < MAXG; ++g) groups[g] = make_int4(0, 0, 0, 0);
    }
    __syncthreads();
    perm[offs[e] + r] = tid;
}

// ============ log-softmax + top-11 + filter + outputs ============
__global__ __launch_bounds__(256) void topk_kernel(
        const float* __restrict__ logits, const int* __restrict__ perm,
        const int* __restrict__ idx, const float* __restrict__ rlp,
        float* __restrict__ out) {
    __shared__ float sl[NL];
    __shared__ float redA[4];
    __shared__ float redB[4];
    __shared__ float bcast[2];
    const int p = blockIdx.x;
    const int tid = threadIdx.x;
    const int b = perm[p];
    const int e = idx[b];
    const float* row = logits + (size_t)p * NL;

    const float4 v4 = *(const float4*)(row + tid * 4);
    *(float4*)&sl[tid * 4] = v4;

    float m = fmaxf(fmaxf(v4.x, v4.y), fmaxf(v4.z, v4.w));
    #pragma unroll
    for (int off = 32; off; off >>= 1) m = fmaxf(m, __shfl_xor(m, off));
    const int wid = tid >> 6;
    if ((tid & 63) == 0) redA[wid] = m;
    __syncthreads();
    if (tid == 0) {
        float mm = redA[0];
        #pragma unroll
        for (int w = 1; w < 4; ++w) mm = fmaxf(mm, redA[w]);
        bcast[0] = mm;
    }
    __syncthreads();
    m = bcast[0];

    float s = expf(v4.x - m) + expf(v4.y - m) + expf(v4.z - m) + expf(v4.w - m);
    #pragma unroll
    for (int off = 32; off; off >>= 1) s += __shfl_xor(s, off);
    if ((tid & 63) == 0) redB[wid] = s;
    __syncthreads();
    if (tid == 0) {
        float ss = 0.f;
        #pragma unroll
        for (int w = 0; w < 4; ++w) ss += redB[w];
        bcast[1] = m + logf(ss);
    }
    __syncthreads();
    const float logZ = bcast[1];

    if (tid < 64) {
        float vals[16];
        #pragma unroll
        for (int q = 0; q < 16; ++q) vals[q] = sl[tid * 16 + q];
        float selv[11];
        int   seli[11];
        for (int t = 0; t < 11; ++t) {
            float v = -INFINITY; int bq = 0;
            #pragma unroll
            for (int q = 0; q < 16; ++q) {
                if (vals[q] > v) { v = vals[q]; bq = q; }  // first occurrence on ties
            }
            int gi = tid * 16 + bq;
            #pragma unroll
            for (int off = 32; off; off >>= 1) {
                const float ov = __shfl_xor(v, off);
                const int   oi = __shfl_xor(gi, off);
                if (ov > v || (ov == v && oi < gi)) { v = ov; gi = oi; }
            }
            selv[t] = v;
            seli[t] = gi;
            if ((gi >> 4) == tid) vals[gi & 15] = -INFINITY;
        }
        if (tid == 0) {
            const float rl = rlp[b];
            int cnt = 0;
            for (int t = 0; t < 11 && cnt < TOPK; ++t) {
                if (seli[t] == 0 && e == 0) continue;  // drop the (0,0) trajectory
                out[(b * TOPK + cnt) * 2 + 0] = (float)e;
                out[(b * TOPK + cnt) * 2 + 1] = (float)seli[t];
                out[Bn * TOPK * 2 + b * TOPK + cnt] = selv[t] - logZ + rl;
                ++cnt;
            }
        }
    }
}

extern "C" void kernel_launch(void* const* d_in, const int* in_sizes, int n_in,
                              void* d_out, int out_size, void* d_ws, size_t ws_size,
                              hipStream_t stream) {
    const float* state = (const float*)d_in[0];
    const float* rW1   = (const float*)d_in[1];
    const float* rb1   = (const float*)d_in[2];
    const float* rW2   = (const float*)d_in[3];
    const float* rb2   = (const float*)d_in[4];
    const float* rW3   = (const float*)d_in[5];
    const float* rb3   = (const float*)d_in[6];
    const float* eW1   = (const float*)d_in[7];
    const float* eb1   = (const float*)d_in[8];
    const float* eW2   = (const float*)d_in[9];
    const float* eb2   = (const float*)d_in[10];
    const float* eW3   = (const float*)d_in[11];
    const float* eb3   = (const float*)d_in[12];
    float* out = (float*)d_out;

    float* eh1    = (float*)d_ws;            // [256][512] (also root h1 scratch)
    float* eh2    = eh1 + Bn * Hm;           // [256][512]
    float* logits = eh2 + Bn * Hm;           // [256][1024] (first half also root h2)
    float* rlp    = logits + Bn * NL;        // [256]
    int*   idxp   = (int*)(rlp + Bn);        // [256]
    int*   perm   = idxp + Bn;               // [256]
    int4*  groups = (int4*)(perm + Bn);      // [88]
    float* rh1 = eh1;      // dead before gL1 writes eh1
    float* rh2 = logits;   // dead before gL3 writes logits

    dense_ks<Dm, Hm, 8, 256, 4, true, false><<<dim3(Bn / 8, Hm / 256), 256, 0, stream>>>(
        state, nullptr, rW1, rb1, nullptr, rh1);
    dense_ks<Hm, Hm, 8, 256, 8, true, false><<<dim3(Bn / 8, Hm / 256), 512, 0, stream>>>(
        rh1, nullptr, rW2, rb2, nullptr, rh2);
    root3_ks<<<Bn / 8, 512, 0, stream>>>(rh2, rW3, rb3, idxp, rlp);
    routing_kernel<<<1, 256, 0, stream>>>(idxp, perm, groups);
    dense_ks<Dm, Hm, 8, 256, 4, true, true><<<dim3(MAXG, Hm / 256), 256, 0, stream>>>(
        state, perm, eW1, eb1, groups, eh1);
    dense_ks<Hm, Hm, 8, 256, 8, true, true><<<dim3(MAXG, Hm / 256), 512, 0, stream>>>(
        eh1, nullptr, eW2, eb2, groups, eh2);
    dense_ks<Hm, NL, 8, 256, 8, false, true><<<dim3(MAXG, NL / 256), 512, 0, stream>>>(
        eh2, nullptr, eW3, eb3, groups, logits);
    topk_kernel<<<Bn, 256, 0, stream>>>(logits, perm, idxp, rlp, out);
}